// Round 19
// baseline (44.829 us; speedup 1.0000x reference)
//
#include <hip/hip_runtime.h>
#include <math.h>

typedef float f32x2 __attribute__((ext_vector_type(2)));
typedef float f32x4 __attribute__((ext_vector_type(4)));

#define TWO_PI 6.283185307179586f
#define SMOOTH 0.1f
#define SPW 16                 // stations per WAVE (doubled: halves wave count)
#define WAVES 2
#define BLOCK 128
#define SPB (SPW * WAVES)      // 32 stations per block; LDS = 46720 B
#define NPAIR 3                // column pairs per thread

__device__ __forceinline__ f32x2 sp2(float x) { f32x2 r; r.x = x; r.y = x; return r; }
__device__ __forceinline__ float rlane(float v, int l) {
    return __uint_as_float((unsigned)__builtin_amdgcn_readlane((int)__float_as_uint(v), l));
}
__device__ __forceinline__ void wait_lgkm() {
    asm volatile("s_waitcnt lgkmcnt(0)" ::: "memory");
}

// v19 = v17 (wave-private slab, wave-local lgkm wait, batched nt full-line
// sweep) with the two prologue cuts R18's regression isolated:
//   1) SPW 8->16, WAVES 4->2: half the waves -> total exposed prologue halves
//      (per-wave prologue instr count unchanged: 64 lanes cover 16 distinct
//      stations instead of 8 x 8-redundant).
//   2) double-angle basis: periods are exact x2 ratios -> 1 sincos + 3
//      doublings per column instead of 4 sincos (runtime-checked fallback).
template<int TT>
__global__ __launch_bounds__(BLOCK) void fused_v19(
    const float* __restrict__ time_vector,
    const float* __restrict__ constant_offset,
    const float* __restrict__ linear_trend,
    const float* __restrict__ amps,      // [N][4]
    const float* __restrict__ phs,       // [N][4]
    const float* __restrict__ wgt,       // [N][K]
    const float* __restrict__ periods,   // [4]
    const int*   __restrict__ nbidx,     // [N][K]
    float* __restrict__ out,             // [N][T]
    int N, int T_rt, int K)
{
    const int T = (TT > 0) ? TT : T_rt;
    extern __shared__ float slab[];      // SPB * T floats (per-wave regions)

    const int tid    = threadIdx.x;
    const int wave   = tid >> 6;
    const int lane   = tid & 63;
    const int wbase  = blockIdx.x * SPB + wave * SPW;

    if (wbase >= N) return;
    int send = N - wbase; if (send > SPW) send = SPW;

    // ---- Phase 1: coefs for station wbase+(lane&15) (16 distinct/wave) ----
    int sid = wbase + (lane & (SPW - 1));
    if (sid >= N) sid = N - 1;

    float4 a = reinterpret_cast<const float4*>(amps)[sid];
    float4 p = reinterpret_cast<const float4*>(phs)[sid];

    int   nb[5]; float w[5];
    __builtin_memcpy(nb, nbidx + (size_t)sid * K, 5 * sizeof(int));
    __builtin_memcpy(w,  wgt   + (size_t)sid * K, 5 * sizeof(float));

    float av0 = 0.f, av1 = 0.f, av2 = 0.f, av3 = 0.f;
    float pv0 = 0.f, pv1 = 0.f, pv2 = 0.f, pv3 = 0.f;
    #pragma unroll
    for (int k = 0; k < 5; ++k) {
        float4 na = reinterpret_cast<const float4*>(amps)[nb[k]];
        float4 np = reinterpret_cast<const float4*>(phs)[nb[k]];
        av0 += w[k] * na.x; av1 += w[k] * na.y; av2 += w[k] * na.z; av3 += w[k] * na.w;
        pv0 += w[k] * np.x; pv1 += w[k] * np.y; pv2 += w[k] * np.z; pv3 += w[k] * np.w;
    }
    float sa0 = (1.0f - SMOOTH) * a.x + SMOOTH * av0;
    float sa1 = (1.0f - SMOOTH) * a.y + SMOOTH * av1;
    float sa2 = (1.0f - SMOOTH) * a.z + SMOOTH * av2;
    float sa3 = (1.0f - SMOOTH) * a.w + SMOOTH * av3;
    float sp0 = (1.0f - SMOOTH) * p.x + SMOOTH * pv0;
    float sp1 = (1.0f - SMOOTH) * p.y + SMOOTH * pv1;
    float sp2v = (1.0f - SMOOTH) * p.z + SMOOTH * pv2;
    float sp3 = (1.0f - SMOOTH) * p.w + SMOOTH * pv3;

    float cc = constant_offset[sid];
    float cm = linear_trend[sid];
    float cA0 = sa0 * __cosf(sp0),  cB0 = sa0 * __sinf(sp0);
    float cA1 = sa1 * __cosf(sp1),  cB1 = sa1 * __sinf(sp1);
    float cA2 = sa2 * __cosf(sp2v), cB2 = sa2 * __sinf(sp2v);
    float cA3 = sa3 * __cosf(sp3),  cB3 = sa3 * __sinf(sp3);

    // ---- Basis: 3 column pairs/thread; double-angle when periods are x2 ----
    const float P0 = periods[0], P1 = periods[1], P2 = periods[2], P3 = periods[3];
    const float w0 = TWO_PI / P0;
    const float w1 = TWO_PI / P1;
    const float w2 = TWO_PI / P2;
    const float w3 = TWO_PI / P3;
    const bool pow2chain = (fabsf(P3 - 2.f * P2) < 1e-6f * P3) &&
                           (fabsf(P2 - 2.f * P1) < 1e-6f * P2) &&
                           (fabsf(P1 - 2.f * P0) < 1e-6f * P1);

    f32x2 tv[NPAIR];
    f32x2 bs[NPAIR][4], bc[NPAIR][4];
    bool full[NPAIR], any[NPAIR];
    const int t0 = 2 * lane;

    #pragma unroll
    for (int q = 0; q < NPAIR; ++q) {
        const int t = t0 + 128 * q;
        const bool v0 = (t < T), v1 = (t + 1 < T);
        any[q] = v0; full[q] = v1;
        float ta = v0 ? time_vector[t]     : 0.f;
        float tb = v1 ? time_vector[t + 1] : 0.f;
        f32x2 tvp; tvp.x = ta; tvp.y = tb;
        tv[q] = tvp;

        if (pow2chain) {
            // base = slowest freq (periods[3]); derive f=2,1,0 by doubling
            float s3a = __sinf(w3 * ta), c3a = __cosf(w3 * ta);
            float s3b = __sinf(w3 * tb), c3b = __cosf(w3 * tb);
            float s2a = 2.f * s3a * c3a, c2a = 1.f - 2.f * s3a * s3a;
            float s2b = 2.f * s3b * c3b, c2b = 1.f - 2.f * s3b * s3b;
            float s1a = 2.f * s2a * c2a, c1a = 1.f - 2.f * s2a * s2a;
            float s1b = 2.f * s2b * c2b, c1b = 1.f - 2.f * s2b * s2b;
            float s0a = 2.f * s1a * c1a, c0a = 1.f - 2.f * s1a * s1a;
            float s0b = 2.f * s1b * c1b, c0b = 1.f - 2.f * s1b * s1b;
            bs[q][0].x = s0a; bs[q][0].y = s0b; bc[q][0].x = c0a; bc[q][0].y = c0b;
            bs[q][1].x = s1a; bs[q][1].y = s1b; bc[q][1].x = c1a; bc[q][1].y = c1b;
            bs[q][2].x = s2a; bs[q][2].y = s2b; bc[q][2].x = c2a; bc[q][2].y = c2b;
            bs[q][3].x = s3a; bs[q][3].y = s3b; bc[q][3].x = c3a; bc[q][3].y = c3b;
        } else {
            #pragma unroll
            for (int f = 0; f < 4; ++f) {
                const float wf = (f == 0) ? w0 : (f == 1) ? w1 : (f == 2) ? w2 : w3;
                f32x2 s, c;
                s.x = __sinf(wf * ta); s.y = __sinf(wf * tb);
                c.x = __cosf(wf * ta); c.y = __cosf(wf * tb);
                bs[q][f] = s; bc[q][f] = c;
            }
        }
    }

    float* wrows = slab + (size_t)(wave * SPW) * T;   // wave-private region

    if (send == SPW) {
        // ---- emit this wave's 16 rows into its private LDS region ----
        #pragma unroll
        for (int j = 0; j < SPW; ++j) {
            float sc  = rlane(cc,  j), sm  = rlane(cm,  j);
            float sA0 = rlane(cA0, j), sB0 = rlane(cB0, j);
            float sA1 = rlane(cA1, j), sB1 = rlane(cB1, j);
            float sA2 = rlane(cA2, j), sB2 = rlane(cB2, j);
            float sA3 = rlane(cA3, j), sB3 = rlane(cB3, j);
            float* lrow = wrows + j * T;

            #pragma unroll
            for (int q = 0; q < NPAIR; ++q) {
                f32x2 sig = sp2(sc) + sp2(sm) * tv[q];
                sig += sp2(sA0) * bs[q][0] + sp2(sB0) * bc[q][0];
                sig += sp2(sA1) * bs[q][1] + sp2(sB1) * bc[q][1];
                sig += sp2(sA2) * bs[q][2] + sp2(sB2) * bc[q][2];
                sig += sp2(sA3) * bs[q][3] + sp2(sB3) * bc[q][3];
                const int t = t0 + 128 * q;
                if (full[q]) { lrow[t] = sig.x; lrow[t + 1] = sig.y; }
                else if (any[q]) { lrow[t] = sig.x; }
            }
        }

        wait_lgkm();   // wave-local drain (no barrier)

        // ---- register-batched nt sweep of MY region ----
        // region = 16*T floats = 4*T chunks (T=365 -> 1460 = 22*64 + 52)
        const f32x4* lsrc = reinterpret_cast<const f32x4*>(wrows);
        f32x4* gdst = reinterpret_cast<f32x4*>(out + (size_t)wbase * T);

        if (TT == 365) {
            #pragma unroll
            for (int half = 0; half < 2; ++half) {
                const int base = half * 704;           // 11*64
                f32x4 v0_ = lsrc[base + lane];        f32x4 v1_ = lsrc[base + lane + 64];
                f32x4 v2_ = lsrc[base + lane + 128];  f32x4 v3_ = lsrc[base + lane + 192];
                f32x4 v4_ = lsrc[base + lane + 256];  f32x4 v5_ = lsrc[base + lane + 320];
                f32x4 v6_ = lsrc[base + lane + 384];  f32x4 v7_ = lsrc[base + lane + 448];
                f32x4 v8_ = lsrc[base + lane + 512];  f32x4 v9_ = lsrc[base + lane + 576];
                f32x4 va_ = lsrc[base + lane + 640];

                __builtin_nontemporal_store(v0_, gdst + base + lane);
                __builtin_nontemporal_store(v1_, gdst + base + lane + 64);
                __builtin_nontemporal_store(v2_, gdst + base + lane + 128);
                __builtin_nontemporal_store(v3_, gdst + base + lane + 192);
                __builtin_nontemporal_store(v4_, gdst + base + lane + 256);
                __builtin_nontemporal_store(v5_, gdst + base + lane + 320);
                __builtin_nontemporal_store(v6_, gdst + base + lane + 384);
                __builtin_nontemporal_store(v7_, gdst + base + lane + 448);
                __builtin_nontemporal_store(v8_, gdst + base + lane + 512);
                __builtin_nontemporal_store(v9_, gdst + base + lane + 576);
                __builtin_nontemporal_store(va_, gdst + base + lane + 640);
            }
            if (lane < 52) {
                f32x4 vr_ = lsrc[1408 + lane];
                __builtin_nontemporal_store(vr_, gdst + 1408 + lane);
            }
        } else {
            const int nch = (SPW * T) >> 2;
            for (int i = lane; i < nch; i += 64) {
                f32x4 v = lsrc[i];
                __builtin_nontemporal_store(v, gdst + i);
            }
        }
    } else {
        // ---- tail path (N % SPW != 0): direct cached stores ----
        float* obase = out + (size_t)wbase * T;
        for (int j = 0; j < send; ++j) {
            float sc  = rlane(cc,  j), sm  = rlane(cm,  j);
            float sA0 = rlane(cA0, j), sB0 = rlane(cB0, j);
            float sA1 = rlane(cA1, j), sB1 = rlane(cB1, j);
            float sA2 = rlane(cA2, j), sB2 = rlane(cB2, j);
            float sA3 = rlane(cA3, j), sB3 = rlane(cB3, j);
            float* orow = obase + (size_t)j * T;
            #pragma unroll
            for (int q = 0; q < NPAIR; ++q) {
                f32x2 sig = sp2(sc) + sp2(sm) * tv[q];
                sig += sp2(sA0) * bs[q][0] + sp2(sB0) * bc[q][0];
                sig += sp2(sA1) * bs[q][1] + sp2(sB1) * bc[q][1];
                sig += sp2(sA2) * bs[q][2] + sp2(sB2) * bc[q][2];
                sig += sp2(sA3) * bs[q][3] + sp2(sB3) * bc[q][3];
                const int t = t0 + 128 * q;
                if (full[q]) { orow[t] = sig.x; orow[t + 1] = sig.y; }
                else if (any[q]) { orow[t] = sig.x; }
            }
        }
    }
}

extern "C" void kernel_launch(void* const* d_in, const int* in_sizes, int n_in,
                              void* d_out, int out_size, void* d_ws, size_t ws_size,
                              hipStream_t stream)
{
    const float* time_vector     = (const float*)d_in[0];
    const float* constant_offset = (const float*)d_in[1];
    const float* linear_trend    = (const float*)d_in[2];
    const float* amps            = (const float*)d_in[3];
    const float* phs             = (const float*)d_in[4];
    const float* wgt             = (const float*)d_in[5];
    const float* periods         = (const float*)d_in[6];
    const int*   nbidx           = (const int*)d_in[7];

    int T = in_sizes[0];
    int N = in_sizes[1];
    int K = in_sizes[5] / N;
    float* out = (float*)d_out;

    int grid = (N + SPB - 1) / SPB;                  // 3125 @ N=100000 (exact)
    size_t shmem = (size_t)SPB * T * sizeof(float);  // 46720 B @ T=365
    if (T == 365) {
        fused_v19<365><<<grid, BLOCK, shmem, stream>>>(
            time_vector, constant_offset, linear_trend, amps, phs, wgt,
            periods, nbidx, out, N, T, K);
    } else {
        fused_v19<0><<<grid, BLOCK, shmem, stream>>>(
            time_vector, constant_offset, linear_trend, amps, phs, wgt,
            periods, nbidx, out, N, T, K);
    }
}

// Round 20
// 39.577 us; speedup vs baseline: 1.1327x; 1.1327x over previous
//
#include <hip/hip_runtime.h>
#include <math.h>

typedef float f32x2 __attribute__((ext_vector_type(2)));
typedef float f32x4 __attribute__((ext_vector_type(4)));

#define TWO_PI 6.283185307179586f
#define SMOOTH 0.1f
#define SPW 8                  // stations per WAVE
#define WAVES 4
#define BLOCK 256
#define SPB (SPW * WAVES)      // 32 stations per block
#define NPAIR 3                // column pairs per thread

__device__ __forceinline__ f32x2 sp2(float x) { f32x2 r; r.x = x; r.y = x; return r; }
__device__ __forceinline__ float rlane(float v, int l) {
    return __uint_as_float((unsigned)__builtin_amdgcn_readlane((int)__float_as_uint(v), l));
}
__device__ __forceinline__ void wait_lgkm() {
    asm volatile("s_waitcnt lgkmcnt(0)" ::: "memory");
}

// v20 = v17 EXACTLY (best: 35.4us — wave-private slab, wave-local lgkm wait,
// register-batched nt full-line sweep, SPW=8/WAVES=4/BLOCK=256) + ONE change:
// double-angle basis. Periods (0.25,0.5,1,2) are exact x2 ratios, so compute
// sincos only for the slowest frequency and derive the other 3 by doubling:
// 24 sincos -> 6 sincos + 18 FMAs per thread (~1/3 of prologue trig removed).
// Runtime pow2chain check falls back to direct sincos.
template<int TT>
__global__ __launch_bounds__(BLOCK) void fused_v20(
    const float* __restrict__ time_vector,
    const float* __restrict__ constant_offset,
    const float* __restrict__ linear_trend,
    const float* __restrict__ amps,      // [N][4]
    const float* __restrict__ phs,       // [N][4]
    const float* __restrict__ wgt,       // [N][K]
    const float* __restrict__ periods,   // [4]
    const int*   __restrict__ nbidx,     // [N][K]
    float* __restrict__ out,             // [N][T]
    int N, int T_rt, int K)
{
    const int T = (TT > 0) ? TT : T_rt;
    extern __shared__ float slab[];      // SPB * T floats (per-wave regions)

    const int tid    = threadIdx.x;
    const int wave   = tid >> 6;
    const int lane   = tid & 63;
    const int wbase  = blockIdx.x * SPB + wave * SPW;

    if (wbase >= N) return;
    int send = N - wbase; if (send > SPW) send = SPW;

    // ---- Phase 1: coefs for station wbase+(lane&7), all lanes redundant ----
    int sid = wbase + (lane & (SPW - 1));
    if (sid >= N) sid = N - 1;

    float4 a = reinterpret_cast<const float4*>(amps)[sid];
    float4 p = reinterpret_cast<const float4*>(phs)[sid];

    int   nb[5]; float w[5];
    __builtin_memcpy(nb, nbidx + (size_t)sid * K, 5 * sizeof(int));
    __builtin_memcpy(w,  wgt   + (size_t)sid * K, 5 * sizeof(float));

    float av0 = 0.f, av1 = 0.f, av2 = 0.f, av3 = 0.f;
    float pv0 = 0.f, pv1 = 0.f, pv2 = 0.f, pv3 = 0.f;
    #pragma unroll
    for (int k = 0; k < 5; ++k) {
        float4 na = reinterpret_cast<const float4*>(amps)[nb[k]];
        float4 np = reinterpret_cast<const float4*>(phs)[nb[k]];
        av0 += w[k] * na.x; av1 += w[k] * na.y; av2 += w[k] * na.z; av3 += w[k] * na.w;
        pv0 += w[k] * np.x; pv1 += w[k] * np.y; pv2 += w[k] * np.z; pv3 += w[k] * np.w;
    }
    float sa0 = (1.0f - SMOOTH) * a.x + SMOOTH * av0;
    float sa1 = (1.0f - SMOOTH) * a.y + SMOOTH * av1;
    float sa2 = (1.0f - SMOOTH) * a.z + SMOOTH * av2;
    float sa3 = (1.0f - SMOOTH) * a.w + SMOOTH * av3;
    float sp0 = (1.0f - SMOOTH) * p.x + SMOOTH * pv0;
    float sp1 = (1.0f - SMOOTH) * p.y + SMOOTH * pv1;
    float sp2v = (1.0f - SMOOTH) * p.z + SMOOTH * pv2;
    float sp3 = (1.0f - SMOOTH) * p.w + SMOOTH * pv3;

    float cc = constant_offset[sid];
    float cm = linear_trend[sid];
    float cA0 = sa0 * __cosf(sp0),  cB0 = sa0 * __sinf(sp0);
    float cA1 = sa1 * __cosf(sp1),  cB1 = sa1 * __sinf(sp1);
    float cA2 = sa2 * __cosf(sp2v), cB2 = sa2 * __sinf(sp2v);
    float cA3 = sa3 * __cosf(sp3),  cB3 = sa3 * __sinf(sp3);

    // ---- Basis: 3 column pairs/thread; double-angle when periods are x2 ----
    const float P0 = periods[0], P1 = periods[1], P2 = periods[2], P3 = periods[3];
    const float w0 = TWO_PI / P0;
    const float w1 = TWO_PI / P1;
    const float w2 = TWO_PI / P2;
    const float w3 = TWO_PI / P3;
    const bool pow2chain = (fabsf(P3 - 2.f * P2) < 1e-6f * P3) &&
                           (fabsf(P2 - 2.f * P1) < 1e-6f * P2) &&
                           (fabsf(P1 - 2.f * P0) < 1e-6f * P1);

    f32x2 tv[NPAIR];
    f32x2 bs[NPAIR][4], bc[NPAIR][4];
    bool full[NPAIR], any[NPAIR];
    const int t0 = 2 * lane;

    #pragma unroll
    for (int q = 0; q < NPAIR; ++q) {
        const int t = t0 + 128 * q;
        const bool v0 = (t < T), v1 = (t + 1 < T);
        any[q] = v0; full[q] = v1;
        float ta = v0 ? time_vector[t]     : 0.f;
        float tb = v1 ? time_vector[t + 1] : 0.f;
        f32x2 tvp; tvp.x = ta; tvp.y = tb;
        tv[q] = tvp;

        if (pow2chain) {
            // base = slowest freq (periods[3]); derive f=2,1,0 by doubling
            float s3a = __sinf(w3 * ta), c3a = __cosf(w3 * ta);
            float s3b = __sinf(w3 * tb), c3b = __cosf(w3 * tb);
            float s2a = 2.f * s3a * c3a, c2a = 1.f - 2.f * s3a * s3a;
            float s2b = 2.f * s3b * c3b, c2b = 1.f - 2.f * s3b * s3b;
            float s1a = 2.f * s2a * c2a, c1a = 1.f - 2.f * s2a * s2a;
            float s1b = 2.f * s2b * c2b, c1b = 1.f - 2.f * s2b * s2b;
            float s0a = 2.f * s1a * c1a, c0a = 1.f - 2.f * s1a * s1a;
            float s0b = 2.f * s1b * c1b, c0b = 1.f - 2.f * s1b * s1b;
            bs[q][0].x = s0a; bs[q][0].y = s0b; bc[q][0].x = c0a; bc[q][0].y = c0b;
            bs[q][1].x = s1a; bs[q][1].y = s1b; bc[q][1].x = c1a; bc[q][1].y = c1b;
            bs[q][2].x = s2a; bs[q][2].y = s2b; bc[q][2].x = c2a; bc[q][2].y = c2b;
            bs[q][3].x = s3a; bs[q][3].y = s3b; bc[q][3].x = c3a; bc[q][3].y = c3b;
        } else {
            #pragma unroll
            for (int f = 0; f < 4; ++f) {
                const float wf = (f == 0) ? w0 : (f == 1) ? w1 : (f == 2) ? w2 : w3;
                f32x2 s, c;
                s.x = __sinf(wf * ta); s.y = __sinf(wf * tb);
                c.x = __cosf(wf * ta); c.y = __cosf(wf * tb);
                bs[q][f] = s; bc[q][f] = c;
            }
        }
    }

    float* wrows = slab + (size_t)(wave * SPW) * T;   // wave-private region

    if (send == SPW) {
        // ---- emit this wave's 8 rows into its private LDS region ----
        #pragma unroll
        for (int j = 0; j < SPW; ++j) {
            float sc  = rlane(cc,  j), sm  = rlane(cm,  j);
            float sA0 = rlane(cA0, j), sB0 = rlane(cB0, j);
            float sA1 = rlane(cA1, j), sB1 = rlane(cB1, j);
            float sA2 = rlane(cA2, j), sB2 = rlane(cB2, j);
            float sA3 = rlane(cA3, j), sB3 = rlane(cB3, j);
            float* lrow = wrows + j * T;

            #pragma unroll
            for (int q = 0; q < NPAIR; ++q) {
                f32x2 sig = sp2(sc) + sp2(sm) * tv[q];
                sig += sp2(sA0) * bs[q][0] + sp2(sB0) * bc[q][0];
                sig += sp2(sA1) * bs[q][1] + sp2(sB1) * bc[q][1];
                sig += sp2(sA2) * bs[q][2] + sp2(sB2) * bc[q][2];
                sig += sp2(sA3) * bs[q][3] + sp2(sB3) * bc[q][3];
                const int t = t0 + 128 * q;
                if (full[q]) { lrow[t] = sig.x; lrow[t + 1] = sig.y; }
                else if (any[q]) { lrow[t] = sig.x; }
            }
        }

        wait_lgkm();   // wave-local: my ds_writes visible to my ds_reads

        // ---- register-batched nt sweep of MY region (no barrier) ----
        // region = 8*T floats = 2*T float4 chunks (T=365 -> 730 = 11*64 + 26)
        const f32x4* lsrc = reinterpret_cast<const f32x4*>(wrows);
        f32x4* gdst = reinterpret_cast<f32x4*>(out + (size_t)wbase * T);

        if (TT == 365) {
            f32x4 v0_ = lsrc[lane];         f32x4 v1_ = lsrc[lane + 64];
            f32x4 v2_ = lsrc[lane + 128];   f32x4 v3_ = lsrc[lane + 192];
            f32x4 v4_ = lsrc[lane + 256];   f32x4 v5_ = lsrc[lane + 320];
            f32x4 v6_ = lsrc[lane + 384];   f32x4 v7_ = lsrc[lane + 448];
            f32x4 v8_ = lsrc[lane + 512];   f32x4 v9_ = lsrc[lane + 576];
            f32x4 va_ = lsrc[lane + 640];
            const bool extra = (lane < 26);
            f32x4 vb_;
            if (extra) vb_ = lsrc[lane + 704];

            __builtin_nontemporal_store(v0_, gdst + lane);
            __builtin_nontemporal_store(v1_, gdst + lane + 64);
            __builtin_nontemporal_store(v2_, gdst + lane + 128);
            __builtin_nontemporal_store(v3_, gdst + lane + 192);
            __builtin_nontemporal_store(v4_, gdst + lane + 256);
            __builtin_nontemporal_store(v5_, gdst + lane + 320);
            __builtin_nontemporal_store(v6_, gdst + lane + 384);
            __builtin_nontemporal_store(v7_, gdst + lane + 448);
            __builtin_nontemporal_store(v8_, gdst + lane + 512);
            __builtin_nontemporal_store(v9_, gdst + lane + 576);
            __builtin_nontemporal_store(va_, gdst + lane + 640);
            if (extra) __builtin_nontemporal_store(vb_, gdst + lane + 704);
        } else {
            const int nch = (SPW * T) >> 2;
            for (int i = lane; i < nch; i += 64) {
                f32x4 v = lsrc[i];
                __builtin_nontemporal_store(v, gdst + i);
            }
        }
    } else {
        // ---- tail path (N % SPW != 0): direct cached stores ----
        float* obase = out + (size_t)wbase * T;
        for (int j = 0; j < send; ++j) {
            float sc  = rlane(cc,  j), sm  = rlane(cm,  j);
            float sA0 = rlane(cA0, j), sB0 = rlane(cB0, j);
            float sA1 = rlane(cA1, j), sB1 = rlane(cB1, j);
            float sA2 = rlane(cA2, j), sB2 = rlane(cB2, j);
            float sA3 = rlane(cA3, j), sB3 = rlane(cB3, j);
            float* orow = obase + (size_t)j * T;
            #pragma unroll
            for (int q = 0; q < NPAIR; ++q) {
                f32x2 sig = sp2(sc) + sp2(sm) * tv[q];
                sig += sp2(sA0) * bs[q][0] + sp2(sB0) * bc[q][0];
                sig += sp2(sA1) * bs[q][1] + sp2(sB1) * bc[q][1];
                sig += sp2(sA2) * bs[q][2] + sp2(sB2) * bc[q][2];
                sig += sp2(sA3) * bs[q][3] + sp2(sB3) * bc[q][3];
                const int t = t0 + 128 * q;
                if (full[q]) { orow[t] = sig.x; orow[t + 1] = sig.y; }
                else if (any[q]) { orow[t] = sig.x; }
            }
        }
    }
}

extern "C" void kernel_launch(void* const* d_in, const int* in_sizes, int n_in,
                              void* d_out, int out_size, void* d_ws, size_t ws_size,
                              hipStream_t stream)
{
    const float* time_vector     = (const float*)d_in[0];
    const float* constant_offset = (const float*)d_in[1];
    const float* linear_trend    = (const float*)d_in[2];
    const float* amps            = (const float*)d_in[3];
    const float* phs             = (const float*)d_in[4];
    const float* wgt             = (const float*)d_in[5];
    const float* periods         = (const float*)d_in[6];
    const int*   nbidx           = (const int*)d_in[7];

    int T = in_sizes[0];
    int N = in_sizes[1];
    int K = in_sizes[5] / N;
    float* out = (float*)d_out;

    int grid = (N + SPB - 1) / SPB;
    size_t shmem = (size_t)SPB * T * sizeof(float);
    if (T == 365) {
        fused_v20<365><<<grid, BLOCK, shmem, stream>>>(
            time_vector, constant_offset, linear_trend, amps, phs, wgt,
            periods, nbidx, out, N, T, K);
    } else {
        fused_v20<0><<<grid, BLOCK, shmem, stream>>>(
            time_vector, constant_offset, linear_trend, amps, phs, wgt,
            periods, nbidx, out, N, T, K);
    }
}

// Round 21
// 35.553 us; speedup vs baseline: 1.2609x; 1.1132x over previous
//
#include <hip/hip_runtime.h>
#include <math.h>

typedef float f32x2 __attribute__((ext_vector_type(2)));
typedef float f32x4 __attribute__((ext_vector_type(4)));

#define TWO_PI 6.283185307179586f
#define SMOOTH 0.1f
#define SPW 8                  // stations per WAVE
#define WAVES 4
#define BLOCK 256
#define SPB (SPW * WAVES)      // 32 stations per block
#define NPAIR 3                // column pairs per thread

__device__ __forceinline__ f32x2 sp2(float x) { f32x2 r; r.x = x; r.y = x; return r; }
__device__ __forceinline__ float rlane(float v, int l) {
    return __uint_as_float((unsigned)__builtin_amdgcn_readlane((int)__float_as_uint(v), l));
}
// Wave-local LDS drain: no s_barrier, no vmcnt. Orders this wave's ds_write
// -> ds_read. (Wave reads only data it wrote itself.)
__device__ __forceinline__ void wait_lgkm() {
    asm volatile("s_waitcnt lgkmcnt(0)" ::: "memory");
}

// v21 = v17 RESTORED VERBATIM (measured best: 35.4 us). Wave-private LDS
// slab, wave-local lgkm wait (no barriers anywhere), register-batched
// nontemporal full-line sweep. The R18-R20 experiments closed every axis
// around this point: occupancy up/down, trig-count cut, compute split,
// block sync, dispatch order all regressed or were null. This is the
// practical optimum for this dispatch shape:
//   ~22 us nt full-line store floor + ~12 us exposed per-wave prologue
//   at the store-concurrency balance point (12 waves/CU).
template<int TT>
__global__ __launch_bounds__(BLOCK) void fused_v17(
    const float* __restrict__ time_vector,
    const float* __restrict__ constant_offset,
    const float* __restrict__ linear_trend,
    const float* __restrict__ amps,      // [N][4]
    const float* __restrict__ phs,       // [N][4]
    const float* __restrict__ wgt,       // [N][K]
    const float* __restrict__ periods,   // [4]
    const int*   __restrict__ nbidx,     // [N][K]
    float* __restrict__ out,             // [N][T]
    int N, int T_rt, int K)
{
    const int T = (TT > 0) ? TT : T_rt;
    extern __shared__ float slab[];      // SPB * T floats (per-wave regions)

    const int tid    = threadIdx.x;
    const int wave   = tid >> 6;
    const int lane   = tid & 63;
    const int wbase  = blockIdx.x * SPB + wave * SPW;

    if (wbase >= N) return;
    int send = N - wbase; if (send > SPW) send = SPW;

    // ---- Phase 1: coefs for station wbase+(lane&7), all lanes redundant ----
    int sid = wbase + (lane & (SPW - 1));
    if (sid >= N) sid = N - 1;

    float4 a = reinterpret_cast<const float4*>(amps)[sid];
    float4 p = reinterpret_cast<const float4*>(phs)[sid];

    int   nb[5]; float w[5];
    __builtin_memcpy(nb, nbidx + (size_t)sid * K, 5 * sizeof(int));
    __builtin_memcpy(w,  wgt   + (size_t)sid * K, 5 * sizeof(float));

    float av0 = 0.f, av1 = 0.f, av2 = 0.f, av3 = 0.f;
    float pv0 = 0.f, pv1 = 0.f, pv2 = 0.f, pv3 = 0.f;
    #pragma unroll
    for (int k = 0; k < 5; ++k) {
        float4 na = reinterpret_cast<const float4*>(amps)[nb[k]];
        float4 np = reinterpret_cast<const float4*>(phs)[nb[k]];
        av0 += w[k] * na.x; av1 += w[k] * na.y; av2 += w[k] * na.z; av3 += w[k] * na.w;
        pv0 += w[k] * np.x; pv1 += w[k] * np.y; pv2 += w[k] * np.z; pv3 += w[k] * np.w;
    }
    float sa0 = (1.0f - SMOOTH) * a.x + SMOOTH * av0;
    float sa1 = (1.0f - SMOOTH) * a.y + SMOOTH * av1;
    float sa2 = (1.0f - SMOOTH) * a.z + SMOOTH * av2;
    float sa3 = (1.0f - SMOOTH) * a.w + SMOOTH * av3;
    float sp0 = (1.0f - SMOOTH) * p.x + SMOOTH * pv0;
    float sp1 = (1.0f - SMOOTH) * p.y + SMOOTH * pv1;
    float sp2v = (1.0f - SMOOTH) * p.z + SMOOTH * pv2;
    float sp3 = (1.0f - SMOOTH) * p.w + SMOOTH * pv3;

    float cc = constant_offset[sid];
    float cm = linear_trend[sid];
    float cA0 = sa0 * __cosf(sp0),  cB0 = sa0 * __sinf(sp0);
    float cA1 = sa1 * __cosf(sp1),  cB1 = sa1 * __sinf(sp1);
    float cA2 = sa2 * __cosf(sp2v), cB2 = sa2 * __sinf(sp2v);
    float cA3 = sa3 * __cosf(sp3),  cB3 = sa3 * __sinf(sp3);

    // ---- Basis: 3 adjacent column pairs per thread, in registers ----
    const float w0 = TWO_PI / periods[0];
    const float w1 = TWO_PI / periods[1];
    const float w2 = TWO_PI / periods[2];
    const float w3 = TWO_PI / periods[3];

    f32x2 tv[NPAIR];
    f32x2 bs[NPAIR][4], bc[NPAIR][4];
    bool full[NPAIR], any[NPAIR];
    const int t0 = 2 * lane;

    #pragma unroll
    for (int q = 0; q < NPAIR; ++q) {
        const int t = t0 + 128 * q;
        const bool v0 = (t < T), v1 = (t + 1 < T);
        any[q] = v0; full[q] = v1;
        float ta = v0 ? time_vector[t]     : 0.f;
        float tb = v1 ? time_vector[t + 1] : 0.f;
        f32x2 tvp; tvp.x = ta; tvp.y = tb;
        tv[q] = tvp;
        #pragma unroll
        for (int f = 0; f < 4; ++f) {
            const float wf = (f == 0) ? w0 : (f == 1) ? w1 : (f == 2) ? w2 : w3;
            f32x2 s, c;
            s.x = __sinf(wf * ta); s.y = __sinf(wf * tb);
            c.x = __cosf(wf * ta); c.y = __cosf(wf * tb);
            bs[q][f] = s; bc[q][f] = c;
        }
    }

    float* wrows = slab + (size_t)(wave * SPW) * T;   // wave-private region

    if (send == SPW) {
        // ---- emit this wave's 8 rows into its private LDS region ----
        #pragma unroll
        for (int j = 0; j < SPW; ++j) {
            float sc  = rlane(cc,  j), sm  = rlane(cm,  j);
            float sA0 = rlane(cA0, j), sB0 = rlane(cB0, j);
            float sA1 = rlane(cA1, j), sB1 = rlane(cB1, j);
            float sA2 = rlane(cA2, j), sB2 = rlane(cB2, j);
            float sA3 = rlane(cA3, j), sB3 = rlane(cB3, j);
            float* lrow = wrows + j * T;

            #pragma unroll
            for (int q = 0; q < NPAIR; ++q) {
                f32x2 sig = sp2(sc) + sp2(sm) * tv[q];
                sig += sp2(sA0) * bs[q][0] + sp2(sB0) * bc[q][0];
                sig += sp2(sA1) * bs[q][1] + sp2(sB1) * bc[q][1];
                sig += sp2(sA2) * bs[q][2] + sp2(sB2) * bc[q][2];
                sig += sp2(sA3) * bs[q][3] + sp2(sB3) * bc[q][3];
                const int t = t0 + 128 * q;
                if (full[q]) { lrow[t] = sig.x; lrow[t + 1] = sig.y; }
                else if (any[q]) { lrow[t] = sig.x; }
            }
        }

        wait_lgkm();   // wave-local: my ds_writes visible to my ds_reads

        // ---- register-batched nt sweep of MY region (no barrier) ----
        // region = 8*T floats = 2*T float4 chunks (T=365 -> 730 = 11*64 + 26)
        const f32x4* lsrc = reinterpret_cast<const f32x4*>(wrows);
        f32x4* gdst = reinterpret_cast<f32x4*>(out + (size_t)wbase * T);

        if (TT == 365) {
            f32x4 v0_ = lsrc[lane];         f32x4 v1_ = lsrc[lane + 64];
            f32x4 v2_ = lsrc[lane + 128];   f32x4 v3_ = lsrc[lane + 192];
            f32x4 v4_ = lsrc[lane + 256];   f32x4 v5_ = lsrc[lane + 320];
            f32x4 v6_ = lsrc[lane + 384];   f32x4 v7_ = lsrc[lane + 448];
            f32x4 v8_ = lsrc[lane + 512];   f32x4 v9_ = lsrc[lane + 576];
            f32x4 va_ = lsrc[lane + 640];
            const bool extra = (lane < 26);
            f32x4 vb_;
            if (extra) vb_ = lsrc[lane + 704];

            __builtin_nontemporal_store(v0_, gdst + lane);
            __builtin_nontemporal_store(v1_, gdst + lane + 64);
            __builtin_nontemporal_store(v2_, gdst + lane + 128);
            __builtin_nontemporal_store(v3_, gdst + lane + 192);
            __builtin_nontemporal_store(v4_, gdst + lane + 256);
            __builtin_nontemporal_store(v5_, gdst + lane + 320);
            __builtin_nontemporal_store(v6_, gdst + lane + 384);
            __builtin_nontemporal_store(v7_, gdst + lane + 448);
            __builtin_nontemporal_store(v8_, gdst + lane + 512);
            __builtin_nontemporal_store(v9_, gdst + lane + 576);
            __builtin_nontemporal_store(va_, gdst + lane + 640);
            if (extra) __builtin_nontemporal_store(vb_, gdst + lane + 704);
        } else {
            const int nch = (SPW * T) >> 2;
            for (int i = lane; i < nch; i += 64) {
                f32x4 v = lsrc[i];
                __builtin_nontemporal_store(v, gdst + i);
            }
        }
    } else {
        // ---- tail path (N % SPW != 0): direct cached stores ----
        float* obase = out + (size_t)wbase * T;
        for (int j = 0; j < send; ++j) {
            float sc  = rlane(cc,  j), sm  = rlane(cm,  j);
            float sA0 = rlane(cA0, j), sB0 = rlane(cB0, j);
            float sA1 = rlane(cA1, j), sB1 = rlane(cB1, j);
            float sA2 = rlane(cA2, j), sB2 = rlane(cB2, j);
            float sA3 = rlane(cA3, j), sB3 = rlane(cB3, j);
            float* orow = obase + (size_t)j * T;
            #pragma unroll
            for (int q = 0; q < NPAIR; ++q) {
                f32x2 sig = sp2(sc) + sp2(sm) * tv[q];
                sig += sp2(sA0) * bs[q][0] + sp2(sB0) * bc[q][0];
                sig += sp2(sA1) * bs[q][1] + sp2(sB1) * bc[q][1];
                sig += sp2(sA2) * bs[q][2] + sp2(sB2) * bc[q][2];
                sig += sp2(sA3) * bs[q][3] + sp2(sB3) * bc[q][3];
                const int t = t0 + 128 * q;
                if (full[q]) { orow[t] = sig.x; orow[t + 1] = sig.y; }
                else if (any[q]) { orow[t] = sig.x; }
            }
        }
    }
}

extern "C" void kernel_launch(void* const* d_in, const int* in_sizes, int n_in,
                              void* d_out, int out_size, void* d_ws, size_t ws_size,
                              hipStream_t stream)
{
    const float* time_vector     = (const float*)d_in[0];
    const float* constant_offset = (const float*)d_in[1];
    const float* linear_trend    = (const float*)d_in[2];
    const float* amps            = (const float*)d_in[3];
    const float* phs             = (const float*)d_in[4];
    const float* wgt             = (const float*)d_in[5];
    const float* periods         = (const float*)d_in[6];
    const int*   nbidx           = (const int*)d_in[7];

    int T = in_sizes[0];
    int N = in_sizes[1];
    int K = in_sizes[5] / N;
    float* out = (float*)d_out;

    int grid = (N + SPB - 1) / SPB;
    size_t shmem = (size_t)SPB * T * sizeof(float);
    if (T == 365) {
        fused_v17<365><<<grid, BLOCK, shmem, stream>>>(
            time_vector, constant_offset, linear_trend, amps, phs, wgt,
            periods, nbidx, out, N, T, K);
    } else {
        fused_v17<0><<<grid, BLOCK, shmem, stream>>>(
            time_vector, constant_offset, linear_trend, amps, phs, wgt,
            periods, nbidx, out, N, T, K);
    }
}